// Round 8
// baseline (169.388 us; speedup 1.0000x reference)
//
#include <hip/hip_runtime.h>
#include <stdint.h>

#define SAMPLES   524288
#define BATCH     16
#define T_FRAMES  2048
#define HOPSZ     256
#define NCH       513
#define KF        512            // folded K (DFT cols 1..512)
#define MF        1152           // folded M: 36 groups of {16 cos | 16 sin}

// workspace layout, single-pass: Wf 1.13 MiB | Sb 32 MiB | Db 32 MiB = 65.1 MiB
#define SB_OFF    1183744
#define DB_OFF_1P (SB_OFF + 33554432)
#define WS_1P     (DB_OFF_1P + 33554432)
#define DB_OFF_2P 17960960       // two-pass fallback (half-size Sb)

typedef __bf16          bf16x8 __attribute__((ext_vector_type(8)));
typedef float           f32x4  __attribute__((ext_vector_type(4)));
typedef unsigned short  u16x8  __attribute__((ext_vector_type(8)));

__device__ __forceinline__ unsigned short f2bf(float f) {
    union { float f; unsigned u; } v; v.f = f;
    unsigned r = v.u + 0x7fffu + ((v.u >> 16) & 1u);   // round-to-nearest-even
    return (unsigned short)(r >> 16);
}

// ---------- prep: weight fold-gather + s/d fold (algebra verified r7) -----
//   re_k = sum_{n=0..511} Wf_s[k,n] * s_t[n],  s_t[n] = x_t[n+1]+x_t[1023-n]
//   im_k = sum_{n=0..511} Wf_d[k,n] * d_t[n],  d_t[n] = x_t[n+1]-x_t[1023-n]
// col 511 = n=512 self-pair (cos weight halved, sin weight exactly 0).
// M layout: group g = {16 cos rows bins g*16+r | 16 sin rows}; invalid rows
// zero -> no bin-0/512 special case in the epilogue.
// blocks [0,wblocks): weight gather (wblocks = 288 or 0).
// blocks [wblocks, ...): fold, 4 frames/block, frames buffer-local.
__global__ void prep(const float* __restrict__ x, const float* __restrict__ wsrc,
                     unsigned short* __restrict__ Wf,
                     unsigned short* __restrict__ Sb,
                     unsigned short* __restrict__ Db,
                     int batch0, int wblocks) {
    int bid = blockIdx.x;
    const int tid = threadIdx.x;
    if (bid < wblocks) {                       // weight gather: 1152 x 512
        int gid = bid * 256 + tid;             // 8 u16 each
        int m   = gid >> 6;
        int n0  = (gid & 63) << 3;
        int g = m >> 5, h = (m >> 4) & 1, r = m & 15;
        int bin = g * 16 + r;
        bool valid = h ? (bin >= 1 && bin <= 511) : (bin <= 512);
        const float* ws = wsrc + (long long)(h ? NCH + bin : bin) * 1024;
        union { u16x8 v; unsigned short e[8]; } o;
        #pragma unroll
        for (int e = 0; e < 8; ++e) {
            int n = n0 + e;
            float v = 0.f;
            if (valid) v = (n < 511) ? ws[n + 1] : 0.5f * ws[512];
            o.e[e] = f2bf(v);
        }
        *(u16x8*)(Wf + (long long)m * KF + n0) = o.v;
        return;
    }
    bid -= wblocks;
    // ---- s/d fold: 4 frames per block, 64 threads per frame (8 cols each)
    const int fr = tid >> 6;
    const int n0 = (tid & 63) << 3;
    const long long f = (long long)bid * 4 + fr;     // buffer-local frame
    const int bat = batch0 + (int)(f >> 11);
    const int t   = (int)(f & 2047);
    const float* xb = x + (long long)bat * SAMPLES;
    float fwd[8], rev[8];
    if (t >= 4) {       // fast path: no pad in window; aligned f32x4 loads
        const f32x4* pf = (const f32x4*)(xb + (t * 256 + n0 - 1024));
        f32x4 A = pf[0], B = pf[1], C = pf[2];
        fwd[0]=A[2]; fwd[1]=A[3]; fwd[2]=B[0]; fwd[3]=B[1];
        fwd[4]=B[2]; fwd[5]=B[3]; fwd[6]=C[0]; fwd[7]=C[1];
        const f32x4* pr = (const f32x4*)(xb + (t * 256 - n0 - 8));
        f32x4 D = pr[0], E = pr[1], F = pr[2];
        rev[0]=F[0]; rev[1]=E[3]; rev[2]=E[2]; rev[3]=E[1];
        rev[4]=E[0]; rev[5]=D[3]; rev[6]=D[2]; rev[7]=D[1];
    } else {            // first 4 frames of each batch touch the zero pad
        #pragma unroll
        for (int e = 0; e < 8; ++e) {
            int n  = n0 + e;
            int pf = t * 256 + n + 1 - 1023;
            int pr = t * 256 - n;
            fwd[e] = (pf >= 0) ? xb[pf] : 0.f;
            rev[e] = (pr >= 0) ? xb[pr] : 0.f;
        }
    }
    union { u16x8 v; unsigned short e[8]; } so, dof;
    #pragma unroll
    for (int e = 0; e < 8; ++e) {
        so.e[e]  = f2bf(fwd[e] + rev[e]);
        dof.e[e] = f2bf(fwd[e] - rev[e]);
    }
    *(u16x8*)(Sb + f * KF + n0) = so.v;
    *(u16x8*)(Db + f * KF + n0) = dof.v;
}

// ---------- async global -> LDS (16 B/lane, dst = wave-uniform base + lane*16)
__device__ __forceinline__ void gll16(const unsigned short* g, unsigned short* s) {
    __builtin_amdgcn_global_load_lds(
        (const __attribute__((address_space(1))) void*)g,
        (__attribute__((address_space(3))) void*)s,
        16, 0, 0);
}

// ---------- folded GEMM + magnitude epilogue ------------------------------
// r2's proven TLP structure (2-barrier 128x128 tile, 16x16x32 MFMA, 0 bank
// conflicts), K=512 fold, A-frags alternate {s-rows, d-rows} per 16. LDS
// 48 KB -> 3 blocks/CU. Single-pass grid: 9 M-tiles x 256 frame-tiles =
// 2304 blocks = EXACTLY 3 rounds of 768 co-resident (r7's 1152 = 1.5 rounds
// paid two ramps). fsh parameterizes frame-tiles-per-XCD (32 single-pass,
// 16 two-pass fallback).
__global__ __launch_bounds__(256, 3)
void stft_gemm(const unsigned short* __restrict__ Sb,
               const unsigned short* __restrict__ Db,
               const unsigned short* __restrict__ Wf,
               float* __restrict__ out, int batch0, int fsh) {
    __shared__ unsigned short Ws[128 * 64];   // 16 KB
    __shared__ unsigned short Ss[128 * 64];   // 16 KB
    __shared__ unsigned short Ds[128 * 64];   // 16 KB

    const int id  = blockIdx.x;
    const int xcd = id & 7;
    const int idx = id >> 3;
    const int nt  = idx >> fsh;                          // 0..8  M tile
    const int ft  = (xcd << fsh) | (idx & ((1 << fsh) - 1));  // buffer frame-tile
    const int t0  = (ft & 15) * 128;
    const long long fl0 = (long long)ft * 128;           // buffer-local frame base

    const int tid = threadIdx.x;
    const int l   = tid & 63;
    const int w   = tid >> 6;
    const int ln  = l & 15;
    const int qd  = l >> 4;

    // staging: wave w stages rows [w*32, w*32+32) of each tile, 4 gll16 per
    // tile; call c: row = w*32 + c*8 + (l>>3), lds chunk = l&7 (implicit),
    // global chunk = (l&7) ^ (row&7).
    const int srow   = l >> 3;
    const int schunk = l & 7;

    const unsigned short* asrc[4];
    const unsigned short* ssrc[4];
    const unsigned short* dsrc[4];
    unsigned short* adst[4];
    unsigned short* sdst[4];
    unsigned short* ddst[4];
    #pragma unroll
    for (int c = 0; c < 4; ++c) {
        int r = w * 32 + c * 8 + srow;
        int gchunk = schunk ^ (r & 7);
        asrc[c] = Wf + (long long)(nt * 128 + r) * KF + gchunk * 8;
        ssrc[c] = Sb + (fl0 + r) * KF + gchunk * 8;
        dsrc[c] = Db + (fl0 + r) * KF + gchunk * 8;
        adst[c] = Ws + (w * 32 + c * 8) * 64;
        sdst[c] = Ss + (w * 32 + c * 8) * 64;
        ddst[c] = Ds + (w * 32 + c * 8) * 64;
    }

    const int wave_m = w & 1;
    const int wave_n = w >> 1;

    f32x4 acc[4][4];
    #pragma unroll
    for (int i = 0; i < 4; ++i)
        #pragma unroll
        for (int j = 0; j < 4; ++j)
            acc[i][j] = (f32x4){0.f, 0.f, 0.f, 0.f};

    // ds_read offsets (identical 0-conflict pattern)
    int a_off[4][2], b_off[4][2];
    #pragma unroll
    for (int i = 0; i < 4; ++i)
        #pragma unroll
        for (int k2 = 0; k2 < 2; ++k2) {
            int ck = ((k2 * 4 + qd) ^ (ln & 7)) * 8;
            a_off[i][k2] = (wave_m * 64 + i * 16 + ln) * 64 + ck;
            b_off[i][k2] = (wave_n * 64 + i * 16 + ln) * 64 + ck;
        }

    for (int kk = 0; kk < KF; kk += 64) {     // 8 K-steps
        #pragma unroll
        for (int c = 0; c < 4; ++c) gll16(asrc[c] + kk, adst[c]);
        #pragma unroll
        for (int c = 0; c < 4; ++c) gll16(ssrc[c] + kk, sdst[c]);
        #pragma unroll
        for (int c = 0; c < 4; ++c) gll16(dsrc[c] + kk, ddst[c]);
        __syncthreads();

        #pragma unroll
        for (int k2 = 0; k2 < 2; ++k2) {
            bf16x8 av[4], bs[4], bd[4];
            #pragma unroll
            for (int i = 0; i < 4; ++i) av[i] = *(const bf16x8*)&Ws[a_off[i][k2]];
            #pragma unroll
            for (int j = 0; j < 4; ++j) bs[j] = *(const bf16x8*)&Ss[b_off[j][k2]];
            #pragma unroll
            for (int j = 0; j < 4; ++j) bd[j] = *(const bf16x8*)&Ds[b_off[j][k2]];
            #pragma unroll
            for (int j = 0; j < 4; ++j) {
                acc[0][j] = __builtin_amdgcn_mfma_f32_16x16x32_bf16(av[0], bs[j], acc[0][j], 0, 0, 0);
                acc[1][j] = __builtin_amdgcn_mfma_f32_16x16x32_bf16(av[1], bd[j], acc[1][j], 0, 0, 0);
                acc[2][j] = __builtin_amdgcn_mfma_f32_16x16x32_bf16(av[2], bs[j], acc[2][j], 0, 0, 0);
                acc[3][j] = __builtin_amdgcn_mfma_f32_16x16x32_bf16(av[3], bd[j], acc[3][j], 0, 0, 0);
            }
        }
        __syncthreads();
    }

    // ---- epilogue: frag pair (2p, 2p+1) = (s=re, d=im) of bin group
    // q = nt*4 + wave_m*2 + p; bin = q*16 + qd*4 + r.
    const int b = batch0 + (ft >> 4);
    float* outb = out + (long long)b * (NCH * T_FRAMES);
    #pragma unroll
    for (int p = 0; p < 2; ++p) {
        #pragma unroll
        for (int j = 0; j < 4; ++j) {
            const int t = t0 + wave_n * 64 + j * 16 + ln;
            #pragma unroll
            for (int r = 0; r < 4; ++r) {
                float re  = acc[2 * p][j][r];
                float im  = acc[2 * p + 1][j][r];
                int bin = (nt * 4 + wave_m * 2 + p) * 16 + qd * 4 + r;
                if (bin < NCH)
                    outb[(long long)bin * T_FRAMES + t] =
                        sqrtf(fmaxf(re * re + im * im, 1e-12f));
            }
        }
    }
}

extern "C" void kernel_launch(void* const* d_in, const int* in_sizes, int n_in,
                              void* d_out, int out_size, void* d_ws, size_t ws_size,
                              hipStream_t stream) {
    const float* x  = (const float*)d_in[0];
    const float* wt = (const float*)d_in[1];
    float* out = (float*)d_out;

    unsigned short* Wf = (unsigned short*)d_ws;
    unsigned short* Sb = (unsigned short*)((char*)d_ws + SB_OFF);

    if (ws_size >= (size_t)WS_1P) {
        // single pass over all 16 batches: 2 dispatches, gemm = exactly 3
        // occupancy rounds (2304 blocks @ 3/CU).
        unsigned short* Db = (unsigned short*)((char*)d_ws + DB_OFF_1P);
        prep<<<288 + 8192, 256, 0, stream>>>(x, wt, Wf, Sb, Db, 0, 288);
        stft_gemm<<<2304, 256, 0, stream>>>(Sb, Db, Wf, out, 0, 5);
    } else {
        // fallback: r7 two-pass (33.1 MiB footprint)
        unsigned short* Db = (unsigned short*)((char*)d_ws + DB_OFF_2P);
        prep<<<288 + 4096, 256, 0, stream>>>(x, wt, Wf, Sb, Db, 0, 288);
        stft_gemm<<<1152, 256, 0, stream>>>(Sb, Db, Wf, out, 0, 4);
        prep<<<4096, 256, 0, stream>>>(x, wt, Wf, Sb, Db, 8, 0);
        stft_gemm<<<1152, 256, 0, stream>>>(Sb, Db, Wf, out, 8, 4);
    }
}

// Round 9
// 151.262 us; speedup vs baseline: 1.1198x; 1.1198x over previous
//
#include <hip/hip_runtime.h>
#include <stdint.h>

#define SAMPLES   524288
#define BATCH     16
#define T_FRAMES  2048
#define HOPSZ     256
#define NCH       513
#define KF        512            // folded K (DFT cols 1..512)
#define MF        1152           // folded M: 36 groups of {16 cos | 16 sin}

// workspace layout, single-pass: Wf 1.13 MiB | Sb 32 MiB | Db 32 MiB = 65.1 MiB
#define SB_OFF    1183744
#define DB_OFF_1P (SB_OFF + 33554432)
#define WS_1P     (DB_OFF_1P + 33554432)
#define DB_OFF_2P 17960960       // two-pass fallback (half-size Sb)

typedef __bf16          bf16x8 __attribute__((ext_vector_type(8)));
typedef float           f32x4  __attribute__((ext_vector_type(4)));
typedef unsigned short  u16x8  __attribute__((ext_vector_type(8)));

__device__ __forceinline__ unsigned short f2bf(float f) {
    union { float f; unsigned u; } v; v.f = f;
    unsigned r = v.u + 0x7fffu + ((v.u >> 16) & 1u);   // round-to-nearest-even
    return (unsigned short)(r >> 16);
}

// ---------- prep: weight fold-gather + s/d fold (passed r7, r8) -----------
//   re_k = sum_{n=0..511} Wf_s[k,n] * s_t[n],  s_t[n] = x_t[n+1]+x_t[1023-n]
//   im_k = sum_{n=0..511} Wf_d[k,n] * d_t[n],  d_t[n] = x_t[n+1]-x_t[1023-n]
// col 511 = n=512 self-pair (cos weight halved, sin weight exactly 0).
// M layout: group g = {16 cos rows bins g*16+r | 16 sin rows}; invalid rows
// zero -> no bin-0/512 special case in the epilogue.
__global__ void prep(const float* __restrict__ x, const float* __restrict__ wsrc,
                     unsigned short* __restrict__ Wf,
                     unsigned short* __restrict__ Sb,
                     unsigned short* __restrict__ Db,
                     int batch0, int wblocks) {
    int bid = blockIdx.x;
    const int tid = threadIdx.x;
    if (bid < wblocks) {                       // weight gather: 1152 x 512
        int gid = bid * 256 + tid;             // 8 u16 each
        int m   = gid >> 6;
        int n0  = (gid & 63) << 3;
        int g = m >> 5, h = (m >> 4) & 1, r = m & 15;
        int bin = g * 16 + r;
        bool valid = h ? (bin >= 1 && bin <= 511) : (bin <= 512);
        const float* ws = wsrc + (long long)(h ? NCH + bin : bin) * 1024;
        union { u16x8 v; unsigned short e[8]; } o;
        #pragma unroll
        for (int e = 0; e < 8; ++e) {
            int n = n0 + e;
            float v = 0.f;
            if (valid) v = (n < 511) ? ws[n + 1] : 0.5f * ws[512];
            o.e[e] = f2bf(v);
        }
        *(u16x8*)(Wf + (long long)m * KF + n0) = o.v;
        return;
    }
    bid -= wblocks;
    // ---- s/d fold: 4 frames per block, 64 threads per frame (8 cols each)
    const int fr = tid >> 6;
    const int n0 = (tid & 63) << 3;
    const long long f = (long long)bid * 4 + fr;     // buffer-local frame
    const int bat = batch0 + (int)(f >> 11);
    const int t   = (int)(f & 2047);
    const float* xb = x + (long long)bat * SAMPLES;
    float fwd[8], rev[8];
    if (t >= 4) {       // fast path: no pad in window; aligned f32x4 loads
        const f32x4* pf = (const f32x4*)(xb + (t * 256 + n0 - 1024));
        f32x4 A = pf[0], B = pf[1], C = pf[2];
        fwd[0]=A[2]; fwd[1]=A[3]; fwd[2]=B[0]; fwd[3]=B[1];
        fwd[4]=B[2]; fwd[5]=B[3]; fwd[6]=C[0]; fwd[7]=C[1];
        const f32x4* pr = (const f32x4*)(xb + (t * 256 - n0 - 8));
        f32x4 D = pr[0], E = pr[1], F = pr[2];
        rev[0]=F[0]; rev[1]=E[3]; rev[2]=E[2]; rev[3]=E[1];
        rev[4]=E[0]; rev[5]=D[3]; rev[6]=D[2]; rev[7]=D[1];
    } else {            // first 4 frames of each batch touch the zero pad
        #pragma unroll
        for (int e = 0; e < 8; ++e) {
            int n  = n0 + e;
            int pf = t * 256 + n + 1 - 1023;
            int pr = t * 256 - n;
            fwd[e] = (pf >= 0) ? xb[pf] : 0.f;
            rev[e] = (pr >= 0) ? xb[pr] : 0.f;
        }
    }
    union { u16x8 v; unsigned short e[8]; } so, dof;
    #pragma unroll
    for (int e = 0; e < 8; ++e) {
        so.e[e]  = f2bf(fwd[e] + rev[e]);
        dof.e[e] = f2bf(fwd[e] - rev[e]);
    }
    *(u16x8*)(Sb + f * KF + n0) = so.v;
    *(u16x8*)(Db + f * KF + n0) = dof.v;
}

// ---------- async global -> LDS (16 B/lane, dst = wave-uniform base + lane*16)
__device__ __forceinline__ void gll16(const unsigned short* g, unsigned short* s) {
    __builtin_amdgcn_global_load_lds(
        (const __attribute__((address_space(1))) void*)g,
        (__attribute__((address_space(3))) void*)s,
        16, 0, 0);
}

// ---------- folded GEMM + magnitude epilogue ------------------------------
// r2's proven TLP structure (2-barrier 128x128 tile, 16x16x32 MFMA, 0 bank
// conflicts), K=512 fold. ROUND-9 CHANGE (r8 post-mortem): block order
// within each XCD is now FT-MAJOR — u = id>>3, ftl = u/9, nt = u%9 — so the
// 9 M-tiles sharing one frame-tile's s/d slice (512 KB) are consecutive,
// co-resident blocks on the same XCD; slice read ~once from HBM instead of
// 9x (r8 measured FETCH 200 MB, MfmaUtil 20%, memory-bound 73 us).
// All 9 weight panels (1.13 MB) stay L2-hot per XCD.
__global__ __launch_bounds__(256, 3)
void stft_gemm(const unsigned short* __restrict__ Sb,
               const unsigned short* __restrict__ Db,
               const unsigned short* __restrict__ Wf,
               float* __restrict__ out, int batch0, int ftpx) {
    __shared__ unsigned short Ws[128 * 64];   // 16 KB
    __shared__ unsigned short Ss[128 * 64];   // 16 KB
    __shared__ unsigned short Ds[128 * 64];   // 16 KB

    const int id  = blockIdx.x;
    const int xcd = id & 7;
    const int u   = id >> 3;
    const int ftl = u / 9;                    // frame-tile local to XCD (fast axis: nt)
    const int nt  = u - ftl * 9;              // 0..8 M tile
    const int ft  = xcd * ftpx + ftl;         // buffer-local frame tile
    const int t0  = (ft & 15) * 128;
    const long long fl0 = (long long)ft * 128;

    const int tid = threadIdx.x;
    const int l   = tid & 63;
    const int w   = tid >> 6;
    const int ln  = l & 15;
    const int qd  = l >> 4;

    // staging: wave w stages rows [w*32, w*32+32) of each tile, 4 gll16 per
    // tile; call c: row = w*32 + c*8 + (l>>3), lds chunk = l&7 (implicit),
    // global chunk = (l&7) ^ (row&7).
    const int srow   = l >> 3;
    const int schunk = l & 7;

    const unsigned short* asrc[4];
    const unsigned short* ssrc[4];
    const unsigned short* dsrc[4];
    unsigned short* adst[4];
    unsigned short* sdst[4];
    unsigned short* ddst[4];
    #pragma unroll
    for (int c = 0; c < 4; ++c) {
        int r = w * 32 + c * 8 + srow;
        int gchunk = schunk ^ (r & 7);
        asrc[c] = Wf + (long long)(nt * 128 + r) * KF + gchunk * 8;
        ssrc[c] = Sb + (fl0 + r) * KF + gchunk * 8;
        dsrc[c] = Db + (fl0 + r) * KF + gchunk * 8;
        adst[c] = Ws + (w * 32 + c * 8) * 64;
        sdst[c] = Ss + (w * 32 + c * 8) * 64;
        ddst[c] = Ds + (w * 32 + c * 8) * 64;
    }

    const int wave_m = w & 1;
    const int wave_n = w >> 1;

    f32x4 acc[4][4];
    #pragma unroll
    for (int i = 0; i < 4; ++i)
        #pragma unroll
        for (int j = 0; j < 4; ++j)
            acc[i][j] = (f32x4){0.f, 0.f, 0.f, 0.f};

    // ds_read offsets (identical 0-conflict pattern)
    int a_off[4][2], b_off[4][2];
    #pragma unroll
    for (int i = 0; i < 4; ++i)
        #pragma unroll
        for (int k2 = 0; k2 < 2; ++k2) {
            int ck = ((k2 * 4 + qd) ^ (ln & 7)) * 8;
            a_off[i][k2] = (wave_m * 64 + i * 16 + ln) * 64 + ck;
            b_off[i][k2] = (wave_n * 64 + i * 16 + ln) * 64 + ck;
        }

    for (int kk = 0; kk < KF; kk += 64) {     // 8 K-steps
        #pragma unroll
        for (int c = 0; c < 4; ++c) gll16(asrc[c] + kk, adst[c]);
        #pragma unroll
        for (int c = 0; c < 4; ++c) gll16(ssrc[c] + kk, sdst[c]);
        #pragma unroll
        for (int c = 0; c < 4; ++c) gll16(dsrc[c] + kk, ddst[c]);
        __syncthreads();

        #pragma unroll
        for (int k2 = 0; k2 < 2; ++k2) {
            bf16x8 av[4], bs[4], bd[4];
            #pragma unroll
            for (int i = 0; i < 4; ++i) av[i] = *(const bf16x8*)&Ws[a_off[i][k2]];
            #pragma unroll
            for (int j = 0; j < 4; ++j) bs[j] = *(const bf16x8*)&Ss[b_off[j][k2]];
            #pragma unroll
            for (int j = 0; j < 4; ++j) bd[j] = *(const bf16x8*)&Ds[b_off[j][k2]];
            #pragma unroll
            for (int j = 0; j < 4; ++j) {
                acc[0][j] = __builtin_amdgcn_mfma_f32_16x16x32_bf16(av[0], bs[j], acc[0][j], 0, 0, 0);
                acc[1][j] = __builtin_amdgcn_mfma_f32_16x16x32_bf16(av[1], bd[j], acc[1][j], 0, 0, 0);
                acc[2][j] = __builtin_amdgcn_mfma_f32_16x16x32_bf16(av[2], bs[j], acc[2][j], 0, 0, 0);
                acc[3][j] = __builtin_amdgcn_mfma_f32_16x16x32_bf16(av[3], bd[j], acc[3][j], 0, 0, 0);
            }
        }
        __syncthreads();
    }

    // ---- epilogue: frag pair (2p, 2p+1) = (s=re, d=im) of bin group
    // q = nt*4 + wave_m*2 + p; bin = q*16 + qd*4 + r.
    const int b = batch0 + (ft >> 4);
    float* outb = out + (long long)b * (NCH * T_FRAMES);
    #pragma unroll
    for (int p = 0; p < 2; ++p) {
        #pragma unroll
        for (int j = 0; j < 4; ++j) {
            const int t = t0 + wave_n * 64 + j * 16 + ln;
            #pragma unroll
            for (int r = 0; r < 4; ++r) {
                float re  = acc[2 * p][j][r];
                float im  = acc[2 * p + 1][j][r];
                int bin = (nt * 4 + wave_m * 2 + p) * 16 + qd * 4 + r;
                if (bin < NCH)
                    outb[(long long)bin * T_FRAMES + t] =
                        sqrtf(fmaxf(re * re + im * im, 1e-12f));
            }
        }
    }
}

extern "C" void kernel_launch(void* const* d_in, const int* in_sizes, int n_in,
                              void* d_out, int out_size, void* d_ws, size_t ws_size,
                              hipStream_t stream) {
    const float* x  = (const float*)d_in[0];
    const float* wt = (const float*)d_in[1];
    float* out = (float*)d_out;

    unsigned short* Wf = (unsigned short*)d_ws;
    unsigned short* Sb = (unsigned short*)((char*)d_ws + SB_OFF);

    if (ws_size >= (size_t)WS_1P) {
        // single pass, ft-major per XCD: 2 dispatches, gemm = 3 exact rounds
        unsigned short* Db = (unsigned short*)((char*)d_ws + DB_OFF_1P);
        prep<<<288 + 8192, 256, 0, stream>>>(x, wt, Wf, Sb, Db, 0, 288);
        stft_gemm<<<2304, 256, 0, stream>>>(Sb, Db, Wf, out, 0, 32);
    } else {
        // fallback: two-pass (33.1 MiB footprint), same ft-major order
        unsigned short* Db = (unsigned short*)((char*)d_ws + DB_OFF_2P);
        prep<<<288 + 4096, 256, 0, stream>>>(x, wt, Wf, Sb, Db, 0, 288);
        stft_gemm<<<1152, 256, 0, stream>>>(Sb, Db, Wf, out, 0, 16);
        prep<<<4096, 256, 0, stream>>>(x, wt, Wf, Sb, Db, 8, 0);
        stft_gemm<<<1152, 256, 0, stream>>>(Sb, Db, Wf, out, 8, 16);
    }
}

// Round 11
// 143.168 us; speedup vs baseline: 1.1831x; 1.0565x over previous
//
#include <hip/hip_runtime.h>
#include <stdint.h>

#define SAMPLES   524288
#define BATCH     16
#define T_FRAMES  2048
#define HOPSZ     256
#define NCH       513
#define KF        512            // folded K (DFT cols 1..512)

// workspace: Wf 1 MiB | Sb 32 MiB | Db 32 MiB
#define SB_OFF    1183744
#define DB_OFF_1P (SB_OFF + 33554432)
#define WS_1P     (DB_OFF_1P + 33554432)
#define DB_OFF_2P 17960960       // two-pass fallback (half-size Sb)

typedef __bf16          bf16x8 __attribute__((ext_vector_type(8)));
typedef float           f32x4  __attribute__((ext_vector_type(4)));
typedef unsigned short  u16x8  __attribute__((ext_vector_type(8)));

__device__ __forceinline__ unsigned short f2bf(float f) {
    union { float f; unsigned u; } v; v.f = f;
    unsigned r = v.u + 0x7fffu + ((v.u >> 16) & 1u);   // round-to-nearest-even
    return (unsigned short)(r >> 16);
}

// ---------- prep: weight fold-gather + s/d fold + bin-512 row -------------
// Fold identity (verified r7-r9): win symmetric, win[0]=0 ->
//   re_k = sum_{n=0..511} Wf_s[k,n] * s_t[n],  s_t[n] = x_t[n+1]+x_t[1023-n]
//   im_k = sum_{n=0..511} Wf_d[k,n] * d_t[n],  d_t[n] = x_t[n+1]-x_t[1023-n]
// col 511 = n=512 self-pair (weight halved since s[511] = 2*x[512]).
// M=1024 GEMM layout: 32 groups of {16 cos bins g*16+r | 16 sin same bins};
// sin(bin0) slot is a TRUE ZERO row (r10 bug: cos512 there multiplied D,
// not S — the fold makes cos/sin slots non-interchangeable). Bin 512
// (s-type, doesn't fit: 513 s-rows vs 512 s-slots) is computed HERE in the
// fold path: one 512-tap dot per frame, wave-reduced, written to out.
__global__ void prep(const float* __restrict__ x, const float* __restrict__ wsrc,
                     unsigned short* __restrict__ Wf,
                     unsigned short* __restrict__ Sb,
                     unsigned short* __restrict__ Db,
                     float* __restrict__ out,
                     int batch0, int wblocks) {
    int bid = blockIdx.x;
    const int tid = threadIdx.x;
    if (bid < wblocks) {                       // weight gather: 1024 x 512
        int gid = bid * 256 + tid;             // 8 u16 each, 256 blocks
        int m   = gid >> 6;                    // 0..1023
        int n0  = (gid & 63) << 3;
        int g = m >> 5, h = (m >> 4) & 1, r = m & 15;
        int bin  = g * 16 + r;                 // 0..511
        bool zero = (h == 1 && bin == 0);      // true zero row (sin0 slot)
        const float* ws = wsrc + (long long)(h ? NCH + bin : bin) * 1024;
        union { u16x8 v; unsigned short e[8]; } o;
        #pragma unroll
        for (int e = 0; e < 8; ++e) {
            int n = n0 + e;
            float v = zero ? 0.f : ((n < 511) ? ws[n + 1] : 0.5f * ws[512]);
            o.e[e] = f2bf(v);
        }
        *(u16x8*)(Wf + (long long)m * KF + n0) = o.v;
        return;
    }
    bid -= wblocks;
    // ---- s/d fold: 4 frames per block, one wave per frame (8 cols/lane)
    const int fr = tid >> 6;
    const int lane = tid & 63;
    const int n0 = lane << 3;
    const long long f = (long long)bid * 4 + fr;     // buffer-local frame
    const int bat = batch0 + (int)(f >> 11);
    const int t   = (int)(f & 2047);
    const float* xb = x + (long long)bat * SAMPLES;
    float fwd[8], rev[8];
    if (t >= 4) {       // fast path: no pad in window; aligned f32x4 loads
        const f32x4* pf = (const f32x4*)(xb + (t * 256 + n0 - 1024));
        f32x4 A = pf[0], B = pf[1], C = pf[2];
        fwd[0]=A[2]; fwd[1]=A[3]; fwd[2]=B[0]; fwd[3]=B[1];
        fwd[4]=B[2]; fwd[5]=B[3]; fwd[6]=C[0]; fwd[7]=C[1];
        const f32x4* pr = (const f32x4*)(xb + (t * 256 - n0 - 8));
        f32x4 D = pr[0], E = pr[1], F = pr[2];
        rev[0]=F[0]; rev[1]=E[3]; rev[2]=E[2]; rev[3]=E[1];
        rev[4]=E[0]; rev[5]=D[3]; rev[6]=D[2]; rev[7]=D[1];
    } else {            // first 4 frames of each batch touch the zero pad
        #pragma unroll
        for (int e = 0; e < 8; ++e) {
            int n  = n0 + e;
            int pf = t * 256 + n + 1 - 1023;
            int pr = t * 256 - n;
            fwd[e] = (pf >= 0) ? xb[pf] : 0.f;
            rev[e] = (pr >= 0) ? xb[pr] : 0.f;
        }
    }
    // bin-512 partial: wf512[n] = cos512row[n+1] (n<511), 0.5*row[512] at 511
    const float* w512 = wsrc + (long long)512 * 1024;
    float p512 = 0.f;
    union { u16x8 v; unsigned short e[8]; } so, dof;
    #pragma unroll
    for (int e = 0; e < 8; ++e) {
        float s = fwd[e] + rev[e];
        float d = fwd[e] - rev[e];
        so.e[e]  = f2bf(s);
        dof.e[e] = f2bf(d);
        int n = n0 + e;
        float wv = (n < 511) ? w512[n + 1] : 0.5f * w512[512];
        p512 += wv * s;
    }
    *(u16x8*)(Sb + f * KF + n0) = so.v;
    *(u16x8*)(Db + f * KF + n0) = dof.v;
    #pragma unroll
    for (int off = 32; off > 0; off >>= 1) p512 += __shfl_xor(p512, off, 64);
    if (lane == 0)
        out[((long long)bat * NCH + 512) * T_FRAMES + t] =
            sqrtf(fmaxf(p512 * p512, 1e-12f));
}

// ---------- async global -> LDS (16 B/lane, dst = wave-uniform base + lane*16)
__device__ __forceinline__ void gll16(const unsigned short* g, unsigned short* s) {
    __builtin_amdgcn_global_load_lds(
        (const __attribute__((address_space(1))) void*)g,
        (__attribute__((address_space(3))) void*)s,
        16, 0, 0);
}

// ---------- folded GEMM + magnitude epilogue ------------------------------
// r10 geometry (never perf-measured; r10 failed on the slot bug, fixed in
// prep): 256x128 tile, 8 waves (4M x 2N), 2 blocks/CU, 66 FLOP/staged-byte
// (r2's proven ratio; r9's 3-tile 128x128 ran 44 -> 33% eff). Per K-step:
// A 32KB by all 8 waves; S by waves 0-3, D by waves 4-7. Same 0-conflict
// per-wave ds_read pattern as r2/r9. Grid 4 nt x 256 ft = 1024 blocks =
// 2 exact rounds, ft-major per XCD (r9-verified: FETCH 200->44 MB).
// A-frag parity: i even = cos rows -> multiply S; i odd = sin rows -> D.
// Epilogue: no special cases (sin0 row is zero -> bin0 im == 0; bin 512
// written by prep).
__global__ __launch_bounds__(512, 4)
void stft_gemm(const unsigned short* __restrict__ Sb,
               const unsigned short* __restrict__ Db,
               const unsigned short* __restrict__ Wf,
               float* __restrict__ out, int batch0, int ftpx) {
    __shared__ unsigned short As[256 * 64];   // 32 KB
    __shared__ unsigned short Ss[128 * 64];   // 16 KB
    __shared__ unsigned short Ds[128 * 64];   // 16 KB

    const int id  = blockIdx.x;
    const int xcd = id & 7;
    const int u   = id >> 3;
    const int ftl = u >> 2;                   // frame-tile local to XCD
    const int nt  = u & 3;                    // M tile fast axis (L2 reuse)
    const int ft  = xcd * ftpx + ftl;         // buffer-local frame tile
    const int t0  = (ft & 15) * 128;
    const long long fl0 = (long long)ft * 128;

    const int tid = threadIdx.x;
    const int l   = tid & 63;
    const int w   = tid >> 6;                 // 0..7
    const int ln  = l & 15;
    const int qd  = l >> 4;

    // staging: A rows [w*32, w*32+32) by wave w; S rows by waves 0-3,
    // D rows by waves 4-7 (wb = w&3). call c: row = base + c*8 + (l>>3),
    // lds chunk = l&7 (implicit), global chunk = (l&7) ^ (row&7).
    const int srow   = l >> 3;
    const int schunk = l & 7;

    const unsigned short* asrc[4];
    const unsigned short* bsrc[4];
    unsigned short* adst[4];
    unsigned short* bdst[4];
    const int wb = w & 3;
    const unsigned short* Bglob = (w < 4) ? Sb : Db;
    unsigned short* Blds = (w < 4) ? Ss : Ds;
    #pragma unroll
    for (int c = 0; c < 4; ++c) {
        int ra = w * 32 + c * 8 + srow;                 // 0..255
        int rb = wb * 32 + c * 8 + srow;                // 0..127
        int gchunk = schunk ^ (srow & 7);               // ra&7 == rb&7 == srow
        asrc[c] = Wf + (long long)(nt * 256 + ra) * KF + gchunk * 8;
        bsrc[c] = Bglob + (fl0 + rb) * KF + gchunk * 8;
        adst[c] = As + (w * 32 + c * 8) * 64;
        bdst[c] = Blds + (wb * 32 + c * 8) * 64;
    }

    const int wave_m = w & 3;                 // 4 M-waves
    const int wave_n = w >> 2;                // 2 N-waves

    f32x4 acc[4][4];
    #pragma unroll
    for (int i = 0; i < 4; ++i)
        #pragma unroll
        for (int j = 0; j < 4; ++j)
            acc[i][j] = (f32x4){0.f, 0.f, 0.f, 0.f};

    // ds_read offsets (identical 0-conflict per-wave pattern to r2/r9)
    int a_off[4][2], b_off[4][2];
    #pragma unroll
    for (int i = 0; i < 4; ++i)
        #pragma unroll
        for (int k2 = 0; k2 < 2; ++k2) {
            int ck = ((k2 * 4 + qd) ^ (ln & 7)) * 8;
            a_off[i][k2] = (wave_m * 64 + i * 16 + ln) * 64 + ck;
            b_off[i][k2] = (wave_n * 64 + i * 16 + ln) * 64 + ck;
        }

    for (int kk = 0; kk < KF; kk += 64) {     // 8 K-steps
        #pragma unroll
        for (int c = 0; c < 4; ++c) gll16(asrc[c] + kk, adst[c]);
        #pragma unroll
        for (int c = 0; c < 4; ++c) gll16(bsrc[c] + kk, bdst[c]);
        __syncthreads();

        #pragma unroll
        for (int k2 = 0; k2 < 2; ++k2) {
            bf16x8 av[4], bs[4], bd[4];
            #pragma unroll
            for (int i = 0; i < 4; ++i) av[i] = *(const bf16x8*)&As[a_off[i][k2]];
            #pragma unroll
            for (int j = 0; j < 4; ++j) bs[j] = *(const bf16x8*)&Ss[b_off[j][k2]];
            #pragma unroll
            for (int j = 0; j < 4; ++j) bd[j] = *(const bf16x8*)&Ds[b_off[j][k2]];
            #pragma unroll
            for (int j = 0; j < 4; ++j) {
                acc[0][j] = __builtin_amdgcn_mfma_f32_16x16x32_bf16(av[0], bs[j], acc[0][j], 0, 0, 0);
                acc[1][j] = __builtin_amdgcn_mfma_f32_16x16x32_bf16(av[1], bd[j], acc[1][j], 0, 0, 0);
                acc[2][j] = __builtin_amdgcn_mfma_f32_16x16x32_bf16(av[2], bs[j], acc[2][j], 0, 0, 0);
                acc[3][j] = __builtin_amdgcn_mfma_f32_16x16x32_bf16(av[3], bd[j], acc[3][j], 0, 0, 0);
            }
        }
        __syncthreads();
    }

    // ---- epilogue: frag pair (2p, 2p+1) = (re, im) of bin group
    // q = nt*8 + wave_m*2 + p; bin = q*16 + qd*4 + r in [0,511], all valid.
    const int b = batch0 + (ft >> 4);
    float* outb = out + (long long)b * (NCH * T_FRAMES);
    #pragma unroll
    for (int p = 0; p < 2; ++p) {
        #pragma unroll
        for (int j = 0; j < 4; ++j) {
            const int t = t0 + wave_n * 64 + j * 16 + ln;
            #pragma unroll
            for (int r = 0; r < 4; ++r) {
                float re  = acc[2 * p][j][r];
                float im  = acc[2 * p + 1][j][r];
                int bin = (nt * 8 + wave_m * 2 + p) * 16 + qd * 4 + r;
                outb[(long long)bin * T_FRAMES + t] =
                    sqrtf(fmaxf(re * re + im * im, 1e-12f));
            }
        }
    }
}

extern "C" void kernel_launch(void* const* d_in, const int* in_sizes, int n_in,
                              void* d_out, int out_size, void* d_ws, size_t ws_size,
                              hipStream_t stream) {
    const float* x  = (const float*)d_in[0];
    const float* wt = (const float*)d_in[1];
    float* out = (float*)d_out;

    unsigned short* Wf = (unsigned short*)d_ws;
    unsigned short* Sb = (unsigned short*)((char*)d_ws + SB_OFF);

    if (ws_size >= (size_t)WS_1P) {
        // single pass: gemm = 1024 blocks = 2 exact rounds at 2 blocks/CU
        unsigned short* Db = (unsigned short*)((char*)d_ws + DB_OFF_1P);
        prep<<<256 + 8192, 256, 0, stream>>>(x, wt, Wf, Sb, Db, out, 0, 256);
        stft_gemm<<<1024, 512, 0, stream>>>(Sb, Db, Wf, out, 0, 32);
    } else {
        // fallback: two-pass (33 MiB footprint), same structure
        unsigned short* Db = (unsigned short*)((char*)d_ws + DB_OFF_2P);
        prep<<<256 + 4096, 256, 0, stream>>>(x, wt, Wf, Sb, Db, out, 0, 256);
        stft_gemm<<<512, 512, 0, stream>>>(Sb, Db, Wf, out, 0, 16);
        prep<<<4096, 256, 0, stream>>>(x, wt, Wf, Sb, Db, out, 8, 0);
        stft_gemm<<<512, 512, 0, stream>>>(Sb, Db, Wf, out, 8, 16);
    }
}